// Round 1
// baseline (169.022 us; speedup 1.0000x reference)
//
#include <hip/hip_runtime.h>

// ---------- problem constants ----------
#define BB 4
#define WW 1024
#define CDIM 1024
#define CCH 32
#define NH 16
#define DH 64
#define MROWS (BB * WW)   // 4096

typedef __bf16 bf16x8 __attribute__((ext_vector_type(8)));
typedef float f32x4 __attribute__((ext_vector_type(4)));

static __device__ __forceinline__ unsigned short f2bf(float f) {
    union { float f; unsigned u; } v; v.f = f;
    unsigned r = v.u + 0x7fffu + ((v.u >> 16) & 1u);
    return (unsigned short)(r >> 16);
}

// ---------- kernel 1: convert weights f32 -> bf16 ----------
// attn_w: 3M elems, proj_w: 1M elems. 4M total. 1M threads x 4 elems (strided).
__global__ __launch_bounds__(256) void convw_kernel(const float* __restrict__ aw,
                                                    const float* __restrict__ pw,
                                                    unsigned short* __restrict__ awb,
                                                    unsigned short* __restrict__ pwb) {
    int i = blockIdx.x * 256 + threadIdx.x;   // 0 .. 1M-1
    const int STRIDE = 4096 * 256;            // 1,048,576
    for (int j = 0; j < 4; ++j) {
        int idx = i + j * STRIDE;             // 0 .. 4M-1
        if (idx < 3 * CDIM * CDIM) {
            awb[idx] = f2bf(aw[idx]);
        } else {
            int k = idx - 3 * CDIM * CDIM;
            pwb[k] = f2bf(pw[k]);
        }
    }
}

// ---------- kernel 2: last-token pool + pos emb ----------
// word[bw, d] = x[bw, last, d] + pos[w, d]; write f32 (d_out) and bf16 (ws)
__global__ __launch_bounds__(256) void pool_kernel(const float* __restrict__ x,
                                                   const float* __restrict__ pos,
                                                   const int* __restrict__ mask,
                                                   float* __restrict__ word_f32,
                                                   unsigned short* __restrict__ word_bf) {
    int bw = blockIdx.x;            // 0..4095
    int w = bw & (WW - 1);
    __shared__ int s_last;
    if (threadIdx.x == 0) {
        int ssum = 0;
        for (int j = 0; j < CCH; ++j) ssum += mask[bw * CCH + j];
        s_last = ssum - 1;          // may be -1 (one_hot(-1) == zeros)
    }
    __syncthreads();
    int last = s_last;
    const float* xr = x + ((size_t)bw * CCH + (last < 0 ? 0 : last)) * CDIM;
    const float* pr = pos + (size_t)w * CDIM;
    for (int d = threadIdx.x; d < CDIM; d += 256) {
        float xv = (last >= 0) ? xr[d] : 0.0f;
        float vv = xv + pr[d];
        word_f32[(size_t)bw * CDIM + d] = vv;
        word_bf[(size_t)bw * CDIM + d] = f2bf(vv);
    }
}

// ---------- GEMM NT: C[m,n] = sum_k A[m,k] * Bt[n,k], bf16 in, 128x128 tile ----------
// EPI 0: scatter qkv (q scaled by 0.125) to [B,H,W,Dh] bf16 buffers
// EPI 1: f32 store to outp[m * Ndim + n]
template <int EPI>
__global__ __launch_bounds__(256) void gemm_nt_kernel(const unsigned short* __restrict__ A,
                                                      const unsigned short* __restrict__ Bt,
                                                      int Mdim, int Ndim, int Kdim,
                                                      unsigned short* __restrict__ qb,
                                                      unsigned short* __restrict__ kb,
                                                      unsigned short* __restrict__ vb,
                                                      float* __restrict__ outp) {
    __shared__ unsigned short As[128 * 32];
    __shared__ unsigned short Bs[128 * 32];
    int t = threadIdx.x;
    int wid = t >> 6, lane = t & 63;
    int wr = wid >> 1, wc = wid & 1;
    int mbase = blockIdx.y * 128, nbase = blockIdx.x * 128;
    int lr = lane & 15, lk = (lane >> 4) * 8;
    f32x4 acc[4][4] = {};
    for (int kt = 0; kt < Kdim; kt += 32) {
        __syncthreads();
        for (int s = 0; s < 2; ++s) {
            int f = s * 256 + t;          // 0..511, 8 bf16 each
            int row = f >> 2, kc = (f & 3) * 8;
            *(int4*)&As[row * 32 + kc] = *(const int4*)&A[(size_t)(mbase + row) * Kdim + kt + kc];
            *(int4*)&Bs[row * 32 + kc] = *(const int4*)&Bt[(size_t)(nbase + row) * Kdim + kt + kc];
        }
        __syncthreads();
        bf16x8 af[4], bfr[4];
        for (int mi = 0; mi < 4; ++mi)
            af[mi] = *(const bf16x8*)&As[(wr * 64 + mi * 16 + lr) * 32 + lk];
        for (int ni = 0; ni < 4; ++ni)
            bfr[ni] = *(const bf16x8*)&Bs[(wc * 64 + ni * 16 + lr) * 32 + lk];
        for (int mi = 0; mi < 4; ++mi)
            for (int ni = 0; ni < 4; ++ni)
                acc[mi][ni] = __builtin_amdgcn_mfma_f32_16x16x32_bf16(af[mi], bfr[ni], acc[mi][ni], 0, 0, 0);
    }
    // epilogue; C/D layout: col = lane&15, row = (lane>>4)*4 + i
    for (int mi = 0; mi < 4; ++mi)
        for (int ni = 0; ni < 4; ++ni)
            for (int i = 0; i < 4; ++i) {
                int row = mbase + wr * 64 + mi * 16 + (lane >> 4) * 4 + i;
                int col = nbase + wc * 64 + ni * 16 + lr;
                float v = acc[mi][ni][i];
                if (EPI == 0) {
                    int sect = col >> 10, ch = col & 1023, hh = ch >> 6, dd = ch & 63;
                    int bI = row >> 10, wI = row & 1023;
                    size_t dst = ((size_t)(bI * NH + hh) * WW + wI) * DH + dd;
                    if (sect == 0) qb[dst] = f2bf(v * 0.125f);   // fold softmax scale (exact pow2)
                    else if (sect == 1) kb[dst] = f2bf(v);
                    else vb[dst] = f2bf(v);
                } else {
                    outp[(size_t)row * Ndim + col] = v;
                }
            }
}

// ---------- kernel 4: causal flash attention ----------
// grid (W/128, B*H); block 256 (4 waves, 32 q-rows each); Dh = 64
__global__ __launch_bounds__(256) void attn_kernel(const unsigned short* __restrict__ q,
                                                   const unsigned short* __restrict__ k,
                                                   const unsigned short* __restrict__ v,
                                                   unsigned short* __restrict__ aout) {
    __shared__ unsigned short Qs[128 * 64];
    __shared__ unsigned short Ks[64 * 64];
    __shared__ unsigned short Vt[64 * 64];   // transposed: Vt[d][kv]
    __shared__ unsigned short Ps[128 * 64];
    int t = threadIdx.x;
    int wid = t >> 6, lane = t & 63;
    int lr = lane & 15, lg = lane >> 4;     // 16-lane group id (0..3)
    int bh = blockIdx.y;
    int bI = bh >> 4, hI = bh & 15;
    int qbase = blockIdx.x * 128;

    // load Q tile (contiguous 128*64 bf16)
    const unsigned short* qg = q + ((size_t)bh * WW + qbase) * DH;
    for (int it = 0; it < 4; ++it) {
        int f = it * 256 + t;
        ((int4*)Qs)[f] = ((const int4*)qg)[f];
    }

    float rm[2][4], rl[2][4];
    f32x4 o[2][4] = {};
    for (int mi = 0; mi < 2; ++mi)
        for (int i = 0; i < 4; ++i) { rm[mi][i] = -1e30f; rl[mi][i] = 0.0f; }

    int nkt = qbase / 64 + 2;    // causal: kv tiles 0 .. qbase/64+1
    for (int kt = 0; kt < nkt; ++kt) {
        __syncthreads();   // previous iter's Vt/Ps reads complete
        const unsigned short* kg = k + ((size_t)bh * WW + kt * 64) * DH;
        const unsigned short* vg = v + ((size_t)bh * WW + kt * 64) * DH;
        for (int it = 0; it < 2; ++it) {
            int f = it * 256 + t;
            ((int4*)Ks)[f] = ((const int4*)kg)[f];
        }
        for (int it = 0; it < 2; ++it) {
            int f = it * 256 + t;           // row kr (0..63), 8 d-values
            int kr = f >> 3, dc = (f & 7) * 8;
            int4 pk = ((const int4*)vg)[f];
            const unsigned short* pv = (const unsigned short*)&pk;
            for (int j = 0; j < 8; ++j) Vt[(dc + j) * 64 + kr] = pv[j];
        }
        __syncthreads();

        // S = Q K^T  (scale already folded into q)
        f32x4 s[2][4] = {};
        for (int ks = 0; ks < 2; ++ks) {
            bf16x8 af[2], bfr[4];
            for (int mi = 0; mi < 2; ++mi)
                af[mi] = *(const bf16x8*)&Qs[(wid * 32 + mi * 16 + lr) * 64 + ks * 32 + lg * 8];
            for (int ni = 0; ni < 4; ++ni)
                bfr[ni] = *(const bf16x8*)&Ks[(ni * 16 + lr) * 64 + ks * 32 + lg * 8];
            for (int mi = 0; mi < 2; ++mi)
                for (int ni = 0; ni < 4; ++ni)
                    s[mi][ni] = __builtin_amdgcn_mfma_f32_16x16x32_bf16(af[mi], bfr[ni], s[mi][ni], 0, 0, 0);
        }

        // causal mask (only needed in diagonal region)
        if (kt * 64 + 63 > qbase + wid * 32) {
            for (int mi = 0; mi < 2; ++mi)
                for (int ni = 0; ni < 4; ++ni)
                    for (int i = 0; i < 4; ++i) {
                        int qi = qbase + wid * 32 + mi * 16 + lg * 4 + i;
                        int ki = kt * 64 + ni * 16 + lr;
                        if (ki > qi) s[mi][ni][i] = -1e30f;
                    }
        }

        // online softmax (rows replicated across each 16-lane group)
        for (int mi = 0; mi < 2; ++mi)
            for (int i = 0; i < 4; ++i) {
                float mx = s[mi][0][i];
                for (int ni = 1; ni < 4; ++ni) mx = fmaxf(mx, s[mi][ni][i]);
                for (int d = 8; d >= 1; d >>= 1) mx = fmaxf(mx, __shfl_xor(mx, d));
                float mnew = fmaxf(rm[mi][i], mx);
                float sf = __expf(rm[mi][i] - mnew);
                float psum = 0.0f;
                for (int ni = 0; ni < 4; ++ni) {
                    float p = __expf(s[mi][ni][i] - mnew);
                    s[mi][ni][i] = p;
                    psum += p;
                }
                for (int d = 8; d >= 1; d >>= 1) psum += __shfl_xor(psum, d);
                rl[mi][i] = rl[mi][i] * sf + psum;
                rm[mi][i] = mnew;
                for (int di = 0; di < 4; ++di) o[mi][di][i] *= sf;
            }

        // write P to LDS (bf16) for PV
        for (int mi = 0; mi < 2; ++mi)
            for (int ni = 0; ni < 4; ++ni)
                for (int i = 0; i < 4; ++i)
                    Ps[(wid * 32 + mi * 16 + lg * 4 + i) * 64 + ni * 16 + lr] = f2bf(s[mi][ni][i]);
        __syncthreads();

        // O += P V
        for (int ks = 0; ks < 2; ++ks) {
            bf16x8 pa[2], vbf[4];
            for (int mi = 0; mi < 2; ++mi)
                pa[mi] = *(const bf16x8*)&Ps[(wid * 32 + mi * 16 + lr) * 64 + ks * 32 + lg * 8];
            for (int di = 0; di < 4; ++di)
                vbf[di] = *(const bf16x8*)&Vt[(di * 16 + lr) * 64 + ks * 32 + lg * 8];
            for (int mi = 0; mi < 2; ++mi)
                for (int di = 0; di < 4; ++di)
                    o[mi][di] = __builtin_amdgcn_mfma_f32_16x16x32_bf16(pa[mi], vbf[di], o[mi][di], 0, 0, 0);
        }
    }

    // epilogue: normalize and store to [B, W, H*Dh] bf16
    for (int mi = 0; mi < 2; ++mi)
        for (int di = 0; di < 4; ++di)
            for (int i = 0; i < 4; ++i) {
                int qrow = qbase + wid * 32 + mi * 16 + lg * 4 + i;
                int dd = di * 16 + lr;
                float val = o[mi][di][i] / rl[mi][i];
                aout[((size_t)bI * WW + qrow) * CDIM + hI * DH + dd] = f2bf(val);
            }
}

// ---------- launch ----------
extern "C" void kernel_launch(void* const* d_in, const int* in_sizes, int n_in,
                              void* d_out, int out_size, void* d_ws, size_t ws_size,
                              hipStream_t stream) {
    const float* x    = (const float*)d_in[0];
    const float* pos  = (const float*)d_in[1];
    const float* aw   = (const float*)d_in[2];
    const float* pw   = (const float*)d_in[3];
    const int*   mask = (const int*)d_in[4];
    float* out = (float*)d_out;
    float* word_f32 = out;                       // [4096,1024] f32
    float* proj_out = out + (size_t)MROWS * CDIM; // [4096,1024] f32

    const size_t MB = 1u << 20;
    char* ws = (char*)d_ws;
    unsigned short* word_bf = (unsigned short*)(ws);             // 8 MB
    unsigned short* awb     = (unsigned short*)(ws + 8 * MB);    // 6 MB
    unsigned short* pwb     = (unsigned short*)(ws + 14 * MB);   // 2 MB
    unsigned short* qb      = (unsigned short*)(ws + 16 * MB);   // 8 MB
    unsigned short* kb      = (unsigned short*)(ws + 24 * MB);   // 8 MB
    unsigned short* vb      = (unsigned short*)(ws + 32 * MB);   // 8 MB
    unsigned short* aob     = (unsigned short*)(ws + 40 * MB);   // 8 MB

    convw_kernel<<<4096, 256, 0, stream>>>(aw, pw, awb, pwb);
    pool_kernel<<<MROWS, 256, 0, stream>>>(x, pos, mask, word_f32, word_bf);
    // QKV: M=4096, N=3072, K=1024
    gemm_nt_kernel<0><<<dim3(3 * CDIM / 128, MROWS / 128), 256, 0, stream>>>(
        word_bf, awb, MROWS, 3 * CDIM, CDIM, qb, kb, vb, nullptr);
    // attention
    attn_kernel<<<dim3(WW / 128, BB * NH), 256, 0, stream>>>(qb, kb, vb, aob);
    // proj: M=4096, N=1024, K=1024
    gemm_nt_kernel<1><<<dim3(CDIM / 128, MROWS / 128), 256, 0, stream>>>(
        aob, pwb, MROWS, CDIM, CDIM, nullptr, nullptr, nullptr, proj_out);
}

// Round 2
// 146.700 us; speedup vs baseline: 1.1522x; 1.1522x over previous
//
#include <hip/hip_runtime.h>

// ---------- problem constants ----------
#define BB 4
#define WW 1024
#define CDIM 1024
#define CCH 32
#define NH 16
#define DH 64
#define MROWS (BB * WW)   // 4096

typedef __bf16 bf16x8 __attribute__((ext_vector_type(8)));
typedef float f32x4 __attribute__((ext_vector_type(4)));

static __device__ __forceinline__ unsigned short f2bf(float f) {
    union { float f; unsigned u; } v; v.f = f;
    unsigned r = v.u + 0x7fffu + ((v.u >> 16) & 1u);
    return (unsigned short)(r >> 16);
}

#if defined(__has_builtin)
#if __has_builtin(__builtin_amdgcn_global_load_lds)
#define HAVE_GLL 1
#endif
#endif

#ifdef HAVE_GLL
static __device__ __forceinline__ void gload16(const void* g, void* l) {
    __builtin_amdgcn_global_load_lds(
        (const __attribute__((address_space(1))) unsigned int*)g,
        (__attribute__((address_space(3))) unsigned int*)l, 16, 0, 0);
}
#endif

// ---------- kernel 1: convert weights f32 -> bf16 (float4 vectorized) ----------
__global__ __launch_bounds__(256) void convw_kernel(const float* __restrict__ aw,
                                                    const float* __restrict__ pw,
                                                    unsigned short* __restrict__ awb,
                                                    unsigned short* __restrict__ pwb) {
    int g = blockIdx.x * 256 + threadIdx.x;   // 0 .. 1M-1 (4M elems / 4)
    const int NA4 = 3 * CDIM * CDIM / 4;      // 786432
    if (g < NA4) {
        float4 vv = ((const float4*)aw)[g];
        ushort4 o = { f2bf(vv.x), f2bf(vv.y), f2bf(vv.z), f2bf(vv.w) };
        ((ushort4*)awb)[g] = o;
    } else {
        int k = g - NA4;
        float4 vv = ((const float4*)pw)[k];
        ushort4 o = { f2bf(vv.x), f2bf(vv.y), f2bf(vv.z), f2bf(vv.w) };
        ((ushort4*)pwb)[k] = o;
    }
}

// ---------- kernel 2: last-token pool + pos emb (float4 vectorized) ----------
__global__ __launch_bounds__(256) void pool_kernel(const float* __restrict__ x,
                                                   const float* __restrict__ pos,
                                                   const int* __restrict__ mask,
                                                   float* __restrict__ word_f32,
                                                   unsigned short* __restrict__ word_bf) {
    int bw = blockIdx.x;            // 0..4095
    int w = bw & (WW - 1);
    __shared__ int s_last;
    if (threadIdx.x == 0) {
        int ssum = 0;
        for (int j = 0; j < CCH; ++j) ssum += mask[bw * CCH + j];
        s_last = ssum - 1;          // may be -1 (one_hot(-1) == zeros)
    }
    __syncthreads();
    int last = s_last;
    const float4* xr = (const float4*)(x + ((size_t)bw * CCH + (last < 0 ? 0 : last)) * CDIM);
    const float4* pr = (const float4*)(pos + (size_t)w * CDIM);
    int d4 = threadIdx.x;           // 256 threads x 4 floats = 1024
    float4 xv = (last >= 0) ? xr[d4] : float4{0.f, 0.f, 0.f, 0.f};
    float4 pv = pr[d4];
    float4 vv = { xv.x + pv.x, xv.y + pv.y, xv.z + pv.z, xv.w + pv.w };
    ((float4*)(word_f32 + (size_t)bw * CDIM))[d4] = vv;
    ushort4 o = { f2bf(vv.x), f2bf(vv.y), f2bf(vv.z), f2bf(vv.w) };
    ((ushort4*)(word_bf + (size_t)bw * CDIM))[d4] = o;
}

// ---------- GEMM NT: C[m,n] = sum_k A[m,k] * Bt[n,k], bf16 in, 128x128 tile ----------
// m97 structure: global_load_lds width-16 staging into linear LDS.
// EPI 0: scatter qkv (q scaled by 0.125) to [B,H,W,Dh] bf16 buffers
// EPI 1: f32 store to outp[m * Ndim + n]
template <int EPI>
__global__ __launch_bounds__(256) void gemm_nt_kernel(const unsigned short* __restrict__ A,
                                                      const unsigned short* __restrict__ Bt,
                                                      int Mdim, int Ndim, int Kdim,
                                                      unsigned short* __restrict__ qb,
                                                      unsigned short* __restrict__ kb,
                                                      unsigned short* __restrict__ vb,
                                                      float* __restrict__ outp) {
    __shared__ unsigned short As[128 * 32];
    __shared__ unsigned short Bs[128 * 32];
    int t = threadIdx.x;
    int wid = t >> 6, lane = t & 63;
    int wr = wid >> 1, wc = wid & 1;
    int mbase = blockIdx.y * 128, nbase = blockIdx.x * 128;
    int lr = lane & 15, lk = (lane >> 4) * 8;
    f32x4 acc[4][4] = {};

#ifdef HAVE_GLL
    // staging geometry: wave w covers rows [w*32, w*32+32) of the 128-row tile,
    // two 16-row instructions each; lane l -> row l>>2, col (l&3)*8
    const unsigned short* Ag = A + (size_t)(mbase + wid * 32 + (lane >> 2)) * Kdim + (lane & 3) * 8;
    const unsigned short* Bg = Bt + (size_t)(nbase + wid * 32 + (lane >> 2)) * Kdim + (lane & 3) * 8;
    unsigned short* As0 = &As[(wid * 32) * 32];
    unsigned short* Bs0 = &Bs[(wid * 32) * 32];
#endif

    for (int kt = 0; kt < Kdim; kt += 32) {
        __syncthreads();
#ifdef HAVE_GLL
        gload16(Ag + kt, As0);
        gload16(Ag + 16 * (size_t)Kdim + kt, As0 + 16 * 32);
        gload16(Bg + kt, Bs0);
        gload16(Bg + 16 * (size_t)Kdim + kt, Bs0 + 16 * 32);
#else
        for (int s = 0; s < 2; ++s) {
            int f = s * 256 + t;
            int row = f >> 2, kc = (f & 3) * 8;
            *(int4*)&As[row * 32 + kc] = *(const int4*)&A[(size_t)(mbase + row) * Kdim + kt + kc];
            *(int4*)&Bs[row * 32 + kc] = *(const int4*)&Bt[(size_t)(nbase + row) * Kdim + kt + kc];
        }
#endif
        __syncthreads();
        bf16x8 af[4], bfr[4];
        for (int mi = 0; mi < 4; ++mi)
            af[mi] = *(const bf16x8*)&As[(wr * 64 + mi * 16 + lr) * 32 + lk];
        for (int ni = 0; ni < 4; ++ni)
            bfr[ni] = *(const bf16x8*)&Bs[(wc * 64 + ni * 16 + lr) * 32 + lk];
        __builtin_amdgcn_s_setprio(1);
        for (int mi = 0; mi < 4; ++mi)
            for (int ni = 0; ni < 4; ++ni)
                acc[mi][ni] = __builtin_amdgcn_mfma_f32_16x16x32_bf16(af[mi], bfr[ni], acc[mi][ni], 0, 0, 0);
        __builtin_amdgcn_s_setprio(0);
    }
    // epilogue; C/D layout: col = lane&15, row = (lane>>4)*4 + i
    for (int mi = 0; mi < 4; ++mi)
        for (int ni = 0; ni < 4; ++ni)
            for (int i = 0; i < 4; ++i) {
                int row = mbase + wr * 64 + mi * 16 + (lane >> 4) * 4 + i;
                int col = nbase + wc * 64 + ni * 16 + lr;
                float v = acc[mi][ni][i];
                if (EPI == 0) {
                    int sect = col >> 10, ch = col & 1023, hh = ch >> 6, dd = ch & 63;
                    int bI = row >> 10, wI = row & 1023;
                    size_t dst = ((size_t)(bI * NH + hh) * WW + wI) * DH + dd;
                    if (sect == 0) qb[dst] = f2bf(v * 0.125f);   // fold softmax scale (exact pow2)
                    else if (sect == 1) kb[dst] = f2bf(v);
                    else vb[dst] = f2bf(v);
                } else {
                    outp[(size_t)row * Ndim + col] = v;
                }
            }
}

// ---------- kernel 4: causal flash attention ----------
// grid (W/128, B*H); block 256 (4 waves, 32 q-rows each); Dh = 64
// All LDS tiles XOR-swizzled: elem(row,col) = row*64 + (col ^ ((row&7)<<3))
__global__ __launch_bounds__(256) void attn_kernel(const unsigned short* __restrict__ q,
                                                   const unsigned short* __restrict__ k,
                                                   const unsigned short* __restrict__ v,
                                                   unsigned short* __restrict__ aout) {
    __shared__ unsigned short Qs[128 * 64];
    __shared__ unsigned short Ks[64 * 64];
    __shared__ unsigned short Vt[64 * 64];   // transposed: Vt[d][kv]
    __shared__ unsigned short Ps[128 * 64];
    int t = threadIdx.x;
    int wid = t >> 6, lane = t & 63;
    int lr = lane & 15, lg = lane >> 4;     // 16-lane group id (0..3)
    int bh = blockIdx.y;
    int bI = bh >> 4, hI = bh & 15;
    int qbase = blockIdx.x * 128;

    // load Q tile (swizzled write)
    const unsigned short* qg = q + ((size_t)bh * WW + qbase) * DH;
    for (int it = 0; it < 4; ++it) {
        int f = it * 256 + t;                  // 1024 int4 = 128 rows x 8
        int row = f >> 3, c8 = (f & 7) * 8;
        *(int4*)&Qs[row * 64 + (c8 ^ ((row & 7) << 3))] = ((const int4*)qg)[f];
    }

    float rm[2][4], rl[2][4];
    f32x4 o[2][4] = {};
    for (int mi = 0; mi < 2; ++mi)
        for (int i = 0; i < 4; ++i) { rm[mi][i] = -1e30f; rl[mi][i] = 0.0f; }

    int nkt = qbase / 64 + 2;    // causal: kv tiles 0 .. qbase/64+1
    for (int kt = 0; kt < nkt; ++kt) {
        __syncthreads();   // previous iter's Vt/Ps reads complete
        const unsigned short* kg = k + ((size_t)bh * WW + kt * 64) * DH;
        const unsigned short* vg = v + ((size_t)bh * WW + kt * 64) * DH;
        for (int it = 0; it < 2; ++it) {
            int f = it * 256 + t;              // 512 int4 = 64 rows x 8
            int row = f >> 3, c8 = (f & 7) * 8;
            *(int4*)&Ks[row * 64 + (c8 ^ ((row & 7) << 3))] = ((const int4*)kg)[f];
        }
        {   // V transpose: 256 threads x {2 rows of Vt, 8 cols each}
            int dp = (t & 31) * 2, kb = t >> 5;  // kb 0..7
            unsigned short va[8], vbv[8];
#pragma unroll
            for (int j = 0; j < 8; ++j) {
                unsigned int wv = *(const unsigned int*)&vg[(size_t)(kb * 8 + j) * 64 + dp];
                va[j] = (unsigned short)(wv & 0xffffu);
                vbv[j] = (unsigned short)(wv >> 16);
            }
            *(int4*)&Vt[dp * 64 + ((kb * 8) ^ ((dp & 7) << 3))] = *(int4*)va;
            int d1 = dp + 1;
            *(int4*)&Vt[d1 * 64 + ((kb * 8) ^ ((d1 & 7) << 3))] = *(int4*)vbv;
        }
        __syncthreads();

        // S = Q K^T  (scale already folded into q)
        f32x4 s[2][4] = {};
        for (int ks = 0; ks < 2; ++ks) {
            bf16x8 af[2], bfr[4];
            for (int mi = 0; mi < 2; ++mi) {
                int row = wid * 32 + mi * 16 + lr;
                af[mi] = *(const bf16x8*)&Qs[row * 64 + ((ks * 32 + lg * 8) ^ ((row & 7) << 3))];
            }
            for (int ni = 0; ni < 4; ++ni) {
                int row = ni * 16 + lr;
                bfr[ni] = *(const bf16x8*)&Ks[row * 64 + ((ks * 32 + lg * 8) ^ ((row & 7) << 3))];
            }
            __builtin_amdgcn_s_setprio(1);
            for (int mi = 0; mi < 2; ++mi)
                for (int ni = 0; ni < 4; ++ni)
                    s[mi][ni] = __builtin_amdgcn_mfma_f32_16x16x32_bf16(af[mi], bfr[ni], s[mi][ni], 0, 0, 0);
            __builtin_amdgcn_s_setprio(0);
        }

        // causal mask (only needed in diagonal region)
        if (kt * 64 + 63 > qbase + wid * 32) {
            for (int mi = 0; mi < 2; ++mi)
                for (int ni = 0; ni < 4; ++ni)
                    for (int i = 0; i < 4; ++i) {
                        int qi = qbase + wid * 32 + mi * 16 + lg * 4 + i;
                        int ki = kt * 64 + ni * 16 + lr;
                        if (ki > qi) s[mi][ni][i] = -1e30f;
                    }
        }

        // online softmax (rows replicated across each 16-lane group)
        for (int mi = 0; mi < 2; ++mi)
            for (int i = 0; i < 4; ++i) {
                float mx = s[mi][0][i];
                for (int ni = 1; ni < 4; ++ni) mx = fmaxf(mx, s[mi][ni][i]);
                for (int d = 8; d >= 1; d >>= 1) mx = fmaxf(mx, __shfl_xor(mx, d));
                float mnew = fmaxf(rm[mi][i], mx);
                float sf = __expf(rm[mi][i] - mnew);
                float psum = 0.0f;
                for (int ni = 0; ni < 4; ++ni) {
                    float p = __expf(s[mi][ni][i] - mnew);
                    s[mi][ni][i] = p;
                    psum += p;
                }
                for (int d = 8; d >= 1; d >>= 1) psum += __shfl_xor(psum, d);
                rl[mi][i] = rl[mi][i] * sf + psum;
                rm[mi][i] = mnew;
                for (int di = 0; di < 4; ++di) o[mi][di][i] *= sf;
            }

        // write P to LDS (bf16, swizzled scalar writes)
        for (int mi = 0; mi < 2; ++mi)
            for (int ni = 0; ni < 4; ++ni)
                for (int i = 0; i < 4; ++i) {
                    int row = wid * 32 + mi * 16 + lg * 4 + i;
                    Ps[row * 64 + ((ni * 16 + lr) ^ ((row & 7) << 3))] = f2bf(s[mi][ni][i]);
                }
        __syncthreads();

        // O += P V
        for (int ks = 0; ks < 2; ++ks) {
            bf16x8 pa[2], vbf[4];
            for (int mi = 0; mi < 2; ++mi) {
                int row = wid * 32 + mi * 16 + lr;
                pa[mi] = *(const bf16x8*)&Ps[row * 64 + ((ks * 32 + lg * 8) ^ ((row & 7) << 3))];
            }
            for (int di = 0; di < 4; ++di) {
                int row = di * 16 + lr;
                vbf[di] = *(const bf16x8*)&Vt[row * 64 + ((ks * 32 + lg * 8) ^ ((row & 7) << 3))];
            }
            __builtin_amdgcn_s_setprio(1);
            for (int mi = 0; mi < 2; ++mi)
                for (int di = 0; di < 4; ++di)
                    o[mi][di] = __builtin_amdgcn_mfma_f32_16x16x32_bf16(pa[mi], vbf[di], o[mi][di], 0, 0, 0);
            __builtin_amdgcn_s_setprio(0);
        }
    }

    // epilogue: normalize and store to [B, W, H*Dh] bf16
    for (int mi = 0; mi < 2; ++mi)
        for (int di = 0; di < 4; ++di)
            for (int i = 0; i < 4; ++i) {
                int qrow = qbase + wid * 32 + mi * 16 + lg * 4 + i;
                int dd = di * 16 + lr;
                float val = o[mi][di][i] / rl[mi][i];
                aout[((size_t)bI * WW + qrow) * CDIM + hI * DH + dd] = f2bf(val);
            }
}

// ---------- launch ----------
extern "C" void kernel_launch(void* const* d_in, const int* in_sizes, int n_in,
                              void* d_out, int out_size, void* d_ws, size_t ws_size,
                              hipStream_t stream) {
    const float* x    = (const float*)d_in[0];
    const float* pos  = (const float*)d_in[1];
    const float* aw   = (const float*)d_in[2];
    const float* pw   = (const float*)d_in[3];
    const int*   mask = (const int*)d_in[4];
    float* out = (float*)d_out;
    float* word_f32 = out;                        // [4096,1024] f32
    float* proj_out = out + (size_t)MROWS * CDIM; // [4096,1024] f32

    const size_t MB = 1u << 20;
    char* ws = (char*)d_ws;
    unsigned short* word_bf = (unsigned short*)(ws);             // 8 MB
    unsigned short* awb     = (unsigned short*)(ws + 8 * MB);    // 6 MB
    unsigned short* pwb     = (unsigned short*)(ws + 14 * MB);   // 2 MB
    unsigned short* qb      = (unsigned short*)(ws + 16 * MB);   // 8 MB
    unsigned short* kb      = (unsigned short*)(ws + 24 * MB);   // 8 MB
    unsigned short* vb      = (unsigned short*)(ws + 32 * MB);   // 8 MB
    unsigned short* aob     = (unsigned short*)(ws + 40 * MB);   // 8 MB

    convw_kernel<<<4096, 256, 0, stream>>>(aw, pw, awb, pwb);
    pool_kernel<<<MROWS, 256, 0, stream>>>(x, pos, mask, word_f32, word_bf);
    // QKV: M=4096, N=3072, K=1024
    gemm_nt_kernel<0><<<dim3(3 * CDIM / 128, MROWS / 128), 256, 0, stream>>>(
        word_bf, awb, MROWS, 3 * CDIM, CDIM, qb, kb, vb, nullptr);
    // attention
    attn_kernel<<<dim3(WW / 128, BB * NH), 256, 0, stream>>>(qb, kb, vb, aob);
    // proj: M=4096, N=1024, K=1024
    gemm_nt_kernel<1><<<dim3(CDIM / 128, MROWS / 128), 256, 0, stream>>>(
        aob, pwb, MROWS, CDIM, CDIM, nullptr, nullptr, nullptr, proj_out);
}

// Round 3
// 114.644 us; speedup vs baseline: 1.4743x; 1.2796x over previous
//
#include <hip/hip_runtime.h>

// ---------- problem constants ----------
#define BB 4
#define WW 1024
#define CDIM 1024
#define CCH 32
#define NH 16
#define DH 64
#define MROWS (BB * WW)   // 4096

typedef __bf16 bf16x8 __attribute__((ext_vector_type(8)));
typedef float f32x4 __attribute__((ext_vector_type(4)));

static __device__ __forceinline__ unsigned short f2bf(float f) {
    union { float f; unsigned u; } v; v.f = f;
    unsigned r = v.u + 0x7fffu + ((v.u >> 16) & 1u);
    return (unsigned short)(r >> 16);
}

#if defined(__has_builtin)
#if __has_builtin(__builtin_amdgcn_global_load_lds)
#define HAVE_GLL 1
#endif
#endif

#ifdef HAVE_GLL
static __device__ __forceinline__ void gload16(const void* g, void* l) {
    __builtin_amdgcn_global_load_lds(
        (const __attribute__((address_space(1))) unsigned int*)g,
        (__attribute__((address_space(3))) unsigned int*)l, 16, 0, 0);
}
#endif

// ---------- kernel 1: convert weights f32 -> bf16 (float4 vectorized) ----------
__global__ __launch_bounds__(256) void convw_kernel(const float* __restrict__ aw,
                                                    const float* __restrict__ pw,
                                                    unsigned short* __restrict__ awb,
                                                    unsigned short* __restrict__ pwb) {
    int g = blockIdx.x * 256 + threadIdx.x;   // 0 .. 1M-1 (4M elems / 4)
    const int NA4 = 3 * CDIM * CDIM / 4;      // 786432
    if (g < NA4) {
        float4 vv = ((const float4*)aw)[g];
        ushort4 o = { f2bf(vv.x), f2bf(vv.y), f2bf(vv.z), f2bf(vv.w) };
        ((ushort4*)awb)[g] = o;
    } else {
        int k = g - NA4;
        float4 vv = ((const float4*)pw)[k];
        ushort4 o = { f2bf(vv.x), f2bf(vv.y), f2bf(vv.z), f2bf(vv.w) };
        ((ushort4*)pwb)[k] = o;
    }
}

// ---------- kernel 2: last-token pool + pos emb (float4 vectorized) ----------
__global__ __launch_bounds__(256) void pool_kernel(const float* __restrict__ x,
                                                   const float* __restrict__ pos,
                                                   const int* __restrict__ mask,
                                                   float* __restrict__ word_f32,
                                                   unsigned short* __restrict__ word_bf) {
    int bw = blockIdx.x;            // 0..4095
    int w = bw & (WW - 1);
    __shared__ int s_last;
    if (threadIdx.x == 0) {
        int ssum = 0;
        for (int j = 0; j < CCH; ++j) ssum += mask[bw * CCH + j];
        s_last = ssum - 1;          // may be -1 (one_hot(-1) == zeros)
    }
    __syncthreads();
    int last = s_last;
    const float4* xr = (const float4*)(x + ((size_t)bw * CCH + (last < 0 ? 0 : last)) * CDIM);
    const float4* pr = (const float4*)(pos + (size_t)w * CDIM);
    int d4 = threadIdx.x;           // 256 threads x 4 floats = 1024
    float4 xv = (last >= 0) ? xr[d4] : float4{0.f, 0.f, 0.f, 0.f};
    float4 pv = pr[d4];
    float4 vv = { xv.x + pv.x, xv.y + pv.y, xv.z + pv.z, xv.w + pv.w };
    ((float4*)(word_f32 + (size_t)bw * CDIM))[d4] = vv;
    ushort4 o = { f2bf(vv.x), f2bf(vv.y), f2bf(vv.z), f2bf(vv.w) };
    ((ushort4*)(word_bf + (size_t)bw * CDIM))[d4] = o;
}

// ---------- GEMM NT: C[m,n] = sum_k A[m,k] * Bt[n,k], bf16 in ----------
// BK=64, swizzled LDS (linear dest + pre-swizzled global source for gload_lds).
// EPI 0: scatter qkv (q scaled by 0.125) to [B,H,W,Dh] bf16 buffers
// EPI 1: f32 store to outp[m * Ndim + n]
template <int EPI, int BM, int BN, int WRN, int WCN, int MI, int NI>
__global__ __launch_bounds__(256) void gemm_nt_kernel(const unsigned short* __restrict__ A,
                                                      const unsigned short* __restrict__ Bt,
                                                      int Mdim, int Ndim, int Kdim,
                                                      unsigned short* __restrict__ qb,
                                                      unsigned short* __restrict__ kb,
                                                      unsigned short* __restrict__ vb,
                                                      float* __restrict__ outp) {
    __shared__ unsigned short As[BM * 64];
    __shared__ unsigned short Bs[BN * 64];
    int t = threadIdx.x;
    int wid = t >> 6, lane = t & 63;
    int wr = wid / WCN, wc = wid % WCN;
    int mbase = blockIdx.y * BM, nbase = blockIdx.x * BN;
    int lr = lane & 15, lg = lane >> 4;
    f32x4 acc[MI][NI] = {};

#ifdef HAVE_GLL
    int csrc = ((lane & 7) ^ (lane >> 3)) * 8;   // pre-swizzled source column
    int rofs = lane >> 3;
    const int TOT = (BM + BN) / 8;               // 8-row chunks of 64 cols (1 KB each)
#endif

    for (int kt = 0; kt < Kdim; kt += 64) {
        __syncthreads();
#ifdef HAVE_GLL
        for (int c = wid; c < TOT; c += 4) {
            if (c < BM / 8)
                gload16(A + (size_t)(mbase + c * 8 + rofs) * Kdim + kt + csrc, &As[c * 8 * 64]);
            else {
                int cb = c - BM / 8;
                gload16(Bt + (size_t)(nbase + cb * 8 + rofs) * Kdim + kt + csrc, &Bs[cb * 8 * 64]);
            }
        }
#else
        for (int s = 0; s < (BM + BN) / 32; ++s) {
            int f = s * 256 + t;
            int row = f >> 3, c8 = (f & 7) * 8;
            if (row < BM)
                *(int4*)&As[row * 64 + (c8 ^ ((row & 7) << 3))] =
                    *(const int4*)&A[(size_t)(mbase + row) * Kdim + kt + c8];
            else {
                int rb = row - BM;
                *(int4*)&Bs[rb * 64 + (c8 ^ ((rb & 7) << 3))] =
                    *(const int4*)&Bt[(size_t)(nbase + rb) * Kdim + kt + c8];
            }
        }
#endif
        __syncthreads();
        for (int ks = 0; ks < 2; ++ks) {
            bf16x8 af[MI], bfr[NI];
            int cc = ks * 32 + lg * 8;
            for (int mi = 0; mi < MI; ++mi) {
                int r = wr * (MI * 16) + mi * 16 + lr;
                af[mi] = *(const bf16x8*)&As[r * 64 + (cc ^ ((r & 7) << 3))];
            }
            for (int ni = 0; ni < NI; ++ni) {
                int r = wc * (NI * 16) + ni * 16 + lr;
                bfr[ni] = *(const bf16x8*)&Bs[r * 64 + (cc ^ ((r & 7) << 3))];
            }
            __builtin_amdgcn_s_setprio(1);
            for (int mi = 0; mi < MI; ++mi)
                for (int ni = 0; ni < NI; ++ni)
                    acc[mi][ni] = __builtin_amdgcn_mfma_f32_16x16x32_bf16(af[mi], bfr[ni], acc[mi][ni], 0, 0, 0);
            __builtin_amdgcn_s_setprio(0);
        }
    }
    // epilogue; C/D layout: col = lane&15, row = (lane>>4)*4 + i
    for (int mi = 0; mi < MI; ++mi)
        for (int ni = 0; ni < NI; ++ni)
            for (int i = 0; i < 4; ++i) {
                int row = mbase + wr * (MI * 16) + mi * 16 + lg * 4 + i;
                int col = nbase + wc * (NI * 16) + ni * 16 + lr;
                float v = acc[mi][ni][i];
                if (EPI == 0) {
                    int sect = col >> 10, ch = col & 1023, hh = ch >> 6, dd = ch & 63;
                    int bI = row >> 10, wI = row & 1023;
                    size_t dst = ((size_t)(bI * NH + hh) * WW + wI) * DH + dd;
                    if (sect == 0) qb[dst] = f2bf(v * 0.125f);   // fold softmax scale (exact pow2)
                    else if (sect == 1) kb[dst] = f2bf(v);
                    else vb[dst] = f2bf(v);
                } else {
                    outp[(size_t)row * Ndim + col] = v;
                }
            }
}

// ---------- kernel 4: causal flash attention, dual q-tile balanced ----------
// grid (4, B*H); block 512 (8 waves, 16 rows per tile each).
// Block p handles q-tiles p (light) and 7-p (heavy): exactly 18 kv-units each.
// K/V staged once, shared by both tiles. Q hoisted to registers.
__global__ __launch_bounds__(512) void attn_kernel(const unsigned short* __restrict__ q,
                                                   const unsigned short* __restrict__ k,
                                                   const unsigned short* __restrict__ v,
                                                   unsigned short* __restrict__ aout) {
    __shared__ unsigned short Ks[64 * 64];
    __shared__ unsigned short Vt[64 * 64];      // transposed: Vt[d][kv]
    __shared__ unsigned short Ps0[128 * 64];
    __shared__ unsigned short Ps1[128 * 64];
    int t = threadIdx.x;
    int wid = t >> 6, lane = t & 63;
    int lr = lane & 15, lg = lane >> 4;
    int bh = blockIdx.y, bI = bh >> 4, hI = bh & 15;
    int p = blockIdx.x;                          // 0..3
    int qa = p * 128, qbv = (7 - p) * 128;
    int nktA = 2 * p + 2, nktB = 16 - 2 * p;

    // hoisted Q fragments (A-operand: rows wid*16+lr, cols ks*32+lg*8)
    bf16x8 qfA[2], qfB[2];
    {
        const unsigned short* qg = q + (size_t)bh * WW * DH;
        int r = wid * 16 + lr;
        for (int ks = 0; ks < 2; ++ks) {
            qfA[ks] = *(const bf16x8*)&qg[(size_t)(qa + r) * DH + ks * 32 + lg * 8];
            qfB[ks] = *(const bf16x8*)&qg[(size_t)(qbv + r) * DH + ks * 32 + lg * 8];
        }
    }

    float rmA[4], rlA[4], rmB[4], rlB[4];
    f32x4 oA[4] = {}, oB[4] = {};
    for (int i = 0; i < 4; ++i) { rmA[i] = rmB[i] = -1e30f; rlA[i] = rlB[i] = 0.f; }

    const unsigned short* kbase = k + (size_t)bh * WW * DH;
    const unsigned short* vbase = v + (size_t)bh * WW * DH;
    // staging split: waves 0-3 transpose V, waves 4-7 load K
    int dp = (t & 31) * 2, kb8 = (t >> 5) & 7;   // V mapping (wid<4)
    int tt = t & 255;                            // K mapping (wid>=4)
    int krow = tt >> 3, kc8 = (tt & 7) * 8;

    unsigned int vr[8]; int4 kr0, kr1;
    auto prefetch = [&](int tn) {
        if (wid < 4) {
            const unsigned short* vg = vbase + (size_t)tn * 64 * DH;
#pragma unroll
            for (int j = 0; j < 8; ++j)
                vr[j] = *(const unsigned int*)&vg[(size_t)(kb8 * 8 + j) * DH + dp];
        } else {
            const unsigned short* kg = kbase + (size_t)tn * 64 * DH;
            kr0 = *(const int4*)&kg[(size_t)krow * DH + kc8];
            kr1 = *(const int4*)&kg[(size_t)(krow + 32) * DH + kc8];
        }
    };
    prefetch(0);

    // per-tile QK + online softmax + P write
    auto process = [&](const bf16x8* qf, int qbase, float* rm, float* rl, f32x4* o,
                       unsigned short* PsX, int tki) {
        f32x4 s[4] = {};
        for (int ks = 0; ks < 2; ++ks) {
            bf16x8 bfr[4];
            int cc = ks * 32 + lg * 8;
            for (int ni = 0; ni < 4; ++ni) {
                int r = ni * 16 + lr;
                bfr[ni] = *(const bf16x8*)&Ks[r * 64 + (cc ^ ((r & 7) << 3))];
            }
            __builtin_amdgcn_s_setprio(1);
            for (int ni = 0; ni < 4; ++ni)
                s[ni] = __builtin_amdgcn_mfma_f32_16x16x32_bf16(qf[ks], bfr[ni], s[ni], 0, 0, 0);
            __builtin_amdgcn_s_setprio(0);
        }
        int rowbase = qbase + wid * 16 + lg * 4;
        if (tki * 64 + 63 > qbase + wid * 16) {
            for (int ni = 0; ni < 4; ++ni)
                for (int i = 0; i < 4; ++i) {
                    int ki = tki * 64 + ni * 16 + lr;
                    if (ki > rowbase + i) s[ni][i] = -1e30f;
                }
        }
        for (int i = 0; i < 4; ++i) {
            float mx = fmaxf(fmaxf(s[0][i], s[1][i]), fmaxf(s[2][i], s[3][i]));
            for (int d = 8; d >= 1; d >>= 1) mx = fmaxf(mx, __shfl_xor(mx, d));
            float mnew = fmaxf(rm[i], mx);
            float sf = __expf(rm[i] - mnew);
            float psum = 0.f;
            for (int ni = 0; ni < 4; ++ni) {
                float pe = __expf(s[ni][i] - mnew);
                s[ni][i] = pe;
                psum += pe;
            }
            for (int d = 8; d >= 1; d >>= 1) psum += __shfl_xor(psum, d);
            rl[i] = rl[i] * sf + psum;
            rm[i] = mnew;
            for (int di = 0; di < 4; ++di) o[di][i] *= sf;
        }
        for (int ni = 0; ni < 4; ++ni)
            for (int i = 0; i < 4; ++i) {
                int r = wid * 16 + lg * 4 + i;
                PsX[r * 64 + ((ni * 16 + lr) ^ ((r & 7) << 3))] = f2bf(s[ni][i]);
            }
    };

    auto pvacc = [&](f32x4* o, const unsigned short* PsX) {
        for (int ks = 0; ks < 2; ++ks) {
            int cc = ks * 32 + lg * 8;
            int r = wid * 16 + lr;
            bf16x8 pa = *(const bf16x8*)&PsX[r * 64 + (cc ^ ((r & 7) << 3))];
            bf16x8 vbf[4];
            for (int di = 0; di < 4; ++di) {
                int rv = di * 16 + lr;
                vbf[di] = *(const bf16x8*)&Vt[rv * 64 + (cc ^ ((rv & 7) << 3))];
            }
            __builtin_amdgcn_s_setprio(1);
            for (int di = 0; di < 4; ++di)
                o[di] = __builtin_amdgcn_mfma_f32_16x16x32_bf16(pa, vbf[di], o[di], 0, 0, 0);
            __builtin_amdgcn_s_setprio(0);
        }
    };

    for (int tki = 0; tki < nktB; ++tki) {
        __syncthreads();   // prev iter's Ks/Vt/Ps reads complete
        if (wid < 4) {
            unsigned short lo[8], hi[8];
#pragma unroll
            for (int j = 0; j < 8; ++j) { lo[j] = (unsigned short)(vr[j] & 0xffffu);
                                          hi[j] = (unsigned short)(vr[j] >> 16); }
            *(int4*)&Vt[dp * 64 + ((kb8 * 8) ^ ((dp & 7) << 3))] = *(int4*)lo;
            int d1 = dp + 1;
            *(int4*)&Vt[d1 * 64 + ((kb8 * 8) ^ ((d1 & 7) << 3))] = *(int4*)hi;
        } else {
            *(int4*)&Ks[krow * 64 + (kc8 ^ ((krow & 7) << 3))] = kr0;
            int r1 = krow + 32;
            *(int4*)&Ks[r1 * 64 + (kc8 ^ ((r1 & 7) << 3))] = kr1;
        }
        if (tki + 1 < nktB) prefetch(tki + 1);   // T14: loads fly under compute
        __syncthreads();

        bool actA = (tki < nktA);
        bool wB = (tki * 64 <= qbv + wid * 16 + 15);   // wave-level diagonal skip
        bool wA = actA && (tki * 64 <= qa + wid * 16 + 15);
        if (wB) process(qfB, qbv, rmB, rlB, oB, Ps1, tki);
        if (wA) process(qfA, qa, rmA, rlA, oA, Ps0, tki);
        __syncthreads();
        if (wB) pvacc(oB, Ps1);
        if (wA) pvacc(oA, Ps0);
    }

    // epilogue: normalize and store to [B, W, H*Dh] bf16
    for (int di = 0; di < 4; ++di)
        for (int i = 0; i < 4; ++i) {
            int dd = di * 16 + lr;
            int qrA = qa + wid * 16 + lg * 4 + i;
            int qrB = qbv + wid * 16 + lg * 4 + i;
            aout[((size_t)bI * WW + qrA) * CDIM + hI * DH + dd] = f2bf(oA[di][i] / rlA[i]);
            aout[((size_t)bI * WW + qrB) * CDIM + hI * DH + dd] = f2bf(oB[di][i] / rlB[i]);
        }
}

// ---------- launch ----------
extern "C" void kernel_launch(void* const* d_in, const int* in_sizes, int n_in,
                              void* d_out, int out_size, void* d_ws, size_t ws_size,
                              hipStream_t stream) {
    const float* x    = (const float*)d_in[0];
    const float* pos  = (const float*)d_in[1];
    const float* aw   = (const float*)d_in[2];
    const float* pw   = (const float*)d_in[3];
    const int*   mask = (const int*)d_in[4];
    float* out = (float*)d_out;
    float* word_f32 = out;                        // [4096,1024] f32
    float* proj_out = out + (size_t)MROWS * CDIM; // [4096,1024] f32

    const size_t MB = 1u << 20;
    char* ws = (char*)d_ws;
    unsigned short* word_bf = (unsigned short*)(ws);             // 8 MB
    unsigned short* awb     = (unsigned short*)(ws + 8 * MB);    // 6 MB
    unsigned short* pwb     = (unsigned short*)(ws + 14 * MB);   // 2 MB
    unsigned short* qb      = (unsigned short*)(ws + 16 * MB);   // 8 MB
    unsigned short* kb      = (unsigned short*)(ws + 24 * MB);   // 8 MB
    unsigned short* vb      = (unsigned short*)(ws + 32 * MB);   // 8 MB
    unsigned short* aob     = (unsigned short*)(ws + 40 * MB);   // 8 MB

    convw_kernel<<<4096, 256, 0, stream>>>(aw, pw, awb, pwb);
    pool_kernel<<<MROWS, 256, 0, stream>>>(x, pos, mask, word_f32, word_bf);
    // QKV: M=4096, N=3072, K=1024; 128x128 tiles, 768 blocks (3/CU)
    gemm_nt_kernel<0, 128, 128, 2, 2, 4, 4><<<dim3(3 * CDIM / 128, MROWS / 128), 256, 0, stream>>>(
        word_bf, awb, MROWS, 3 * CDIM, CDIM, qb, kb, vb, nullptr);
    // attention: dual q-tile balanced, 256 blocks (1/CU), 512 threads
    attn_kernel<<<dim3(4, BB * NH), 512, 0, stream>>>(qb, kb, vb, aob);
    // proj: M=4096, N=1024, K=1024; 128x64 tiles, 512 blocks (2/CU)
    gemm_nt_kernel<1, 128, 64, 4, 1, 2, 4><<<dim3(CDIM / 64, MROWS / 128), 256, 0, stream>>>(
        aob, pwb, MROWS, CDIM, CDIM, nullptr, nullptr, nullptr, proj_out);
}

// Round 5
// 112.604 us; speedup vs baseline: 1.5010x; 1.0181x over previous
//
#include <hip/hip_runtime.h>

// ---------- problem constants ----------
#define BB 4
#define WW 1024
#define CDIM 1024
#define CCH 32
#define NH 16
#define DH 64
#define MROWS (BB * WW)   // 4096

typedef __bf16 bf16x8 __attribute__((ext_vector_type(8)));
typedef float f32x4 __attribute__((ext_vector_type(4)));

static __device__ __forceinline__ unsigned short f2bf(float f) {
    union { float f; unsigned u; } v; v.f = f;
    unsigned r = v.u + 0x7fffu + ((v.u >> 16) & 1u);
    return (unsigned short)(r >> 16);
}

#if defined(__has_builtin)
#if __has_builtin(__builtin_amdgcn_global_load_lds)
#define HAVE_GLL 1
#endif
#endif

#ifdef HAVE_GLL
static __device__ __forceinline__ void gload16(const void* g, void* l) {
    __builtin_amdgcn_global_load_lds(
        (const __attribute__((address_space(1))) unsigned int*)g,
        (__attribute__((address_space(3))) unsigned int*)l, 16, 0, 0);
}
#endif

// ---------- kernel 1: fused weight-convert + pool (independent halves) ----------
__global__ __launch_bounds__(256) void prep_kernel(const float* __restrict__ aw,
                                                   const float* __restrict__ pw,
                                                   const float* __restrict__ x,
                                                   const float* __restrict__ pos,
                                                   const int* __restrict__ mask,
                                                   unsigned short* __restrict__ awb,
                                                   unsigned short* __restrict__ pwb,
                                                   float* __restrict__ word_f32,
                                                   unsigned short* __restrict__ word_bf) {
    int blk = blockIdx.x;
    if (blk < 4096) {
        int g = blk * 256 + threadIdx.x;          // 0 .. 1M-1
        const int NA4 = 3 * CDIM * CDIM / 4;      // 786432
        if (g < NA4) {
            float4 vv = ((const float4*)aw)[g];
            ushort4 o = { f2bf(vv.x), f2bf(vv.y), f2bf(vv.z), f2bf(vv.w) };
            ((ushort4*)awb)[g] = o;
        } else {
            int kk = g - NA4;
            float4 vv = ((const float4*)pw)[kk];
            ushort4 o = { f2bf(vv.x), f2bf(vv.y), f2bf(vv.z), f2bf(vv.w) };
            ((ushort4*)pwb)[kk] = o;
        }
    } else {
        int bw = blk - 4096;            // 0..4095
        int w = bw & (WW - 1);
        __shared__ int s_last;
        if (threadIdx.x == 0) {
            int ssum = 0;
            for (int j = 0; j < CCH; ++j) ssum += mask[bw * CCH + j];
            s_last = ssum - 1;          // may be -1 (one_hot(-1) == zeros)
        }
        __syncthreads();
        int last = s_last;
        const float4* xr = (const float4*)(x + ((size_t)bw * CCH + (last < 0 ? 0 : last)) * CDIM);
        const float4* pr = (const float4*)(pos + (size_t)w * CDIM);
        int d4 = threadIdx.x;
        float4 xv = (last >= 0) ? xr[d4] : float4{0.f, 0.f, 0.f, 0.f};
        float4 pv = pr[d4];
        float4 vv = { xv.x + pv.x, xv.y + pv.y, xv.z + pv.z, xv.w + pv.w };
        ((float4*)(word_f32 + (size_t)bw * CDIM))[d4] = vv;
        ushort4 o = { f2bf(vv.x), f2bf(vv.y), f2bf(vv.z), f2bf(vv.w) };
        ((ushort4*)(word_bf + (size_t)bw * CDIM))[d4] = o;
    }
}

#ifdef HAVE_GLL
// ---------- QKV GEMM, deep-pipelined, BM=256 BN=192 BK=64, dynamic LDS ----------
// 512 threads (8 waves, 2M x 4N; wave tile 128x48). Double-buffered (A depth-2,
// B depth-3), raw s_barrier, counted s_waitcnt vmcnt(3) once per K-tile.
// Phase cadence (per tile t): p0: reads B(all)+A01, stage t+1.A01
//                             p1: reads A23,        stage t+1.A23
//                             p2: reads A45,        stage t+2.B01
//                             p3: reads A67,        stage t+2.B2, vmcnt(3)
#define NTK 16
#define BUFS 28672   // shorts per buffer: A [0,16384) + B [16384,28672)
__global__ __launch_bounds__(512) void gemm_qkv8_kernel(const unsigned short* __restrict__ A,
                                                        const unsigned short* __restrict__ Bt,
                                                        unsigned short* __restrict__ qb,
                                                        unsigned short* __restrict__ kb,
                                                        unsigned short* __restrict__ vb) {
    extern __shared__ unsigned short L[];
    const int K = 1024;
    int t = threadIdx.x, wid = t >> 6, lane = t & 63;
    int wm = wid >> 2, wn = wid & 3;
    int lr = lane & 15, lg = lane >> 4;
    int mbase = blockIdx.y * 256, nbase = blockIdx.x * 192;
    int srow = lane >> 3;
    int scol = ((lane & 7) ^ (lane >> 3)) * 8;          // pre-swizzled source col

    const unsigned short* Abase = A + (size_t)(mbase + wid * 8 + srow) * K + scol;
    const unsigned short* Bbase = Bt + (size_t)(nbase + wid * 8 + srow) * K + scol;

#define STAGE_A(buf, unit, tile) \
    gload16(Abase + (size_t)(unit) * 64 * K + (tile) * 64, \
            &L[(buf) * BUFS + (unit) * 4096 + wid * 512])
#define STAGE_B(buf, unit, tile) \
    gload16(Bbase + (size_t)(unit) * 64 * K + (tile) * 64, \
            &L[(buf) * BUFS + 16384 + (unit) * 4096 + wid * 512])
#define LDA(mi_, ks_) (*(const bf16x8*)&L[c * BUFS + (wm * 128 + (mi_) * 16 + lr) * 64 + \
                        (((ks_) * 32 + lg * 8) ^ ((lr & 7) << 3))])
#define LDB(ni_, ks_) (*(const bf16x8*)&L[c * BUFS + 16384 + (wn * 48 + (ni_) * 16 + lr) * 64 + \
                        (((ks_) * 32 + lg * 8) ^ ((lr & 7) << 3))])
#define PRE_MFMA() do { __builtin_amdgcn_s_barrier(); \
    asm volatile("s_waitcnt lgkmcnt(0)" ::: "memory"); \
    __builtin_amdgcn_sched_barrier(0); \
    __builtin_amdgcn_s_setprio(1); } while (0)
#define POST_MFMA() do { __builtin_amdgcn_s_setprio(0); \
    __builtin_amdgcn_s_barrier(); } while (0)

    f32x4 acc[8][3] = {};

    // prologue: tile0 A+B, tile1 B; keep tile1.B (3 loads) in flight
    STAGE_A(0, 0, 0); STAGE_A(0, 1, 0); STAGE_A(0, 2, 0); STAGE_A(0, 3, 0);
    STAGE_B(0, 0, 0); STAGE_B(0, 1, 0); STAGE_B(0, 2, 0);
    STAGE_B(1, 0, 1); STAGE_B(1, 1, 1); STAGE_B(1, 2, 1);
    asm volatile("s_waitcnt vmcnt(3)" ::: "memory");
    __builtin_amdgcn_s_barrier();

    for (int tk = 0; tk < NTK; ++tk) {
        int c = tk & 1;
        bf16x8 bfr[3][2], af[2][2];

        // ---- phase 0
#pragma unroll
        for (int ni = 0; ni < 3; ++ni)
#pragma unroll
            for (int ks = 0; ks < 2; ++ks)
                bfr[ni][ks] = LDB(ni, ks);
#pragma unroll
        for (int ks = 0; ks < 2; ++ks) { af[0][ks] = LDA(0, ks); af[1][ks] = LDA(1, ks); }
        if (tk + 1 < NTK) { STAGE_A(c ^ 1, 0, tk + 1); STAGE_A(c ^ 1, 1, tk + 1); }
        PRE_MFMA();
#pragma unroll
        for (int ni = 0; ni < 3; ++ni)
#pragma unroll
            for (int ks = 0; ks < 2; ++ks) {
                acc[0][ni] = __builtin_amdgcn_mfma_f32_16x16x32_bf16(af[0][ks], bfr[ni][ks], acc[0][ni], 0, 0, 0);
                acc[1][ni] = __builtin_amdgcn_mfma_f32_16x16x32_bf16(af[1][ks], bfr[ni][ks], acc[1][ni], 0, 0, 0);
            }
        POST_MFMA();

        // ---- phase 1
#pragma unroll
        for (int ks = 0; ks < 2; ++ks) { af[0][ks] = LDA(2, ks); af[1][ks] = LDA(3, ks); }
        if (tk + 1 < NTK) { STAGE_A(c ^ 1, 2, tk + 1); STAGE_A(c ^ 1, 3, tk + 1); }
        PRE_MFMA();
#pragma unroll
        for (int ni = 0; ni < 3; ++ni)
#pragma unroll
            for (int ks = 0; ks < 2; ++ks) {
                acc[2][ni] = __builtin_amdgcn_mfma_f32_16x16x32_bf16(af[0][ks], bfr[ni][ks], acc[2][ni], 0, 0, 0);
                acc[3][ni] = __builtin_amdgcn_mfma_f32_16x16x32_bf16(af[1][ks], bfr[ni][ks], acc[3][ni], 0, 0, 0);
            }
        POST_MFMA();

        // ---- phase 2
#pragma unroll
        for (int ks = 0; ks < 2; ++ks) { af[0][ks] = LDA(4, ks); af[1][ks] = LDA(5, ks); }
        if (tk + 2 < NTK) { STAGE_B(c, 0, tk + 2); STAGE_B(c, 1, tk + 2); }
        PRE_MFMA();
#pragma unroll
        for (int ni = 0; ni < 3; ++ni)
#pragma unroll
            for (int ks = 0; ks < 2; ++ks) {
                acc[4][ni] = __builtin_amdgcn_mfma_f32_16x16x32_bf16(af[0][ks], bfr[ni][ks], acc[4][ni], 0, 0, 0);
                acc[5][ni] = __builtin_amdgcn_mfma_f32_16x16x32_bf16(af[1][ks], bfr[ni][ks], acc[5][ni], 0, 0, 0);
            }
        POST_MFMA();

        // ---- phase 3
#pragma unroll
        for (int ks = 0; ks < 2; ++ks) { af[0][ks] = LDA(6, ks); af[1][ks] = LDA(7, ks); }
        if (tk + 2 < NTK) { STAGE_B(c, 2, tk + 2); }
        PRE_MFMA();
#pragma unroll
        for (int ni = 0; ni < 3; ++ni)
#pragma unroll
            for (int ks = 0; ks < 2; ++ks) {
                acc[6][ni] = __builtin_amdgcn_mfma_f32_16x16x32_bf16(af[0][ks], bfr[ni][ks], acc[6][ni], 0, 0, 0);
                acc[7][ni] = __builtin_amdgcn_mfma_f32_16x16x32_bf16(af[1][ks], bfr[ni][ks], acc[7][ni], 0, 0, 0);
            }
        __builtin_amdgcn_s_setprio(0);
        if (tk + 2 < NTK) { asm volatile("s_waitcnt vmcnt(3)" ::: "memory"); }
        else              { asm volatile("s_waitcnt vmcnt(0)" ::: "memory"); }
        __builtin_amdgcn_s_barrier();
    }

    // epilogue: scatter q/k/v (q scaled by 0.125)
#pragma unroll
    for (int mi = 0; mi < 8; ++mi)
#pragma unroll
        for (int ni = 0; ni < 3; ++ni)
#pragma unroll
            for (int i = 0; i < 4; ++i) {
                int row = mbase + wm * 128 + mi * 16 + lg * 4 + i;
                int col = nbase + wn * 48 + ni * 16 + lr;
                float v = acc[mi][ni][i];
                int sect = col >> 10, ch = col & 1023, hh = ch >> 6, dd = ch & 63;
                int bI = row >> 10, wI = row & 1023;
                size_t dst = ((size_t)(bI * NH + hh) * WW + wI) * DH + dd;
                if (sect == 0) qb[dst] = f2bf(v * 0.125f);
                else if (sect == 1) kb[dst] = f2bf(v);
                else vb[dst] = f2bf(v);
            }
#undef STAGE_A
#undef STAGE_B
#undef LDA
#undef LDB
#undef PRE_MFMA
#undef POST_MFMA
}
#endif  // HAVE_GLL

// ---------- GEMM NT (round-3 structure): proj + QKV fallback ----------
template <int EPI, int BM, int BN, int WRN, int WCN, int MI, int NI>
__global__ __launch_bounds__(256) void gemm_nt_kernel(const unsigned short* __restrict__ A,
                                                      const unsigned short* __restrict__ Bt,
                                                      int Mdim, int Ndim, int Kdim,
                                                      unsigned short* __restrict__ qb,
                                                      unsigned short* __restrict__ kb,
                                                      unsigned short* __restrict__ vb,
                                                      float* __restrict__ outp) {
    __shared__ unsigned short As[BM * 64];
    __shared__ unsigned short Bs[BN * 64];
    int t = threadIdx.x;
    int wid = t >> 6, lane = t & 63;
    int wr = wid / WCN, wc = wid % WCN;
    int mbase = blockIdx.y * BM, nbase = blockIdx.x * BN;
    int lr = lane & 15, lg = lane >> 4;
    f32x4 acc[MI][NI] = {};

#ifdef HAVE_GLL
    int csrc = ((lane & 7) ^ (lane >> 3)) * 8;
    int rofs = lane >> 3;
    const int TOT = (BM + BN) / 8;
#endif

    for (int kt = 0; kt < Kdim; kt += 64) {
        __syncthreads();
#ifdef HAVE_GLL
        for (int cch = wid; cch < TOT; cch += 4) {
            if (cch < BM / 8)
                gload16(A + (size_t)(mbase + cch * 8 + rofs) * Kdim + kt + csrc, &As[cch * 8 * 64]);
            else {
                int cb = cch - BM / 8;
                gload16(Bt + (size_t)(nbase + cb * 8 + rofs) * Kdim + kt + csrc, &Bs[cb * 8 * 64]);
            }
        }
#else
        for (int s = 0; s < (BM + BN) / 32; ++s) {
            int f = s * 256 + t;
            int row = f >> 3, c8 = (f & 7) * 8;
            if (row < BM)
                *(int4*)&As[row * 64 + (c8 ^ ((row & 7) << 3))] =
                    *(const int4*)&A[(size_t)(mbase + row) * Kdim + kt + c8];
            else {
                int rb = row - BM;
                *(int4*)&Bs[rb * 64 + (c8 ^ ((rb & 7) << 3))] =
                    *(const int4*)&Bt[(size_t)(nbase + rb) * Kdim + kt + c8];
            }
        }
#endif
        __syncthreads();
        for (int ks = 0; ks < 2; ++ks) {
            bf16x8 af[MI], bfr[NI];
            int cc = ks * 32 + lg * 8;
            for (int mi = 0; mi < MI; ++mi) {
                int r = wr * (MI * 16) + mi * 16 + lr;
                af[mi] = *(const bf16x8*)&As[r * 64 + (cc ^ ((r & 7) << 3))];
            }
            for (int ni = 0; ni < NI; ++ni) {
                int r = wc * (NI * 16) + ni * 16 + lr;
                bfr[ni] = *(const bf16x8*)&Bs[r * 64 + (cc ^ ((r & 7) << 3))];
            }
            __builtin_amdgcn_s_setprio(1);
            for (int mi = 0; mi < MI; ++mi)
                for (int ni = 0; ni < NI; ++ni)
                    acc[mi][ni] = __builtin_amdgcn_mfma_f32_16x16x32_bf16(af[mi], bfr[ni], acc[mi][ni], 0, 0, 0);
            __builtin_amdgcn_s_setprio(0);
        }
    }
    for (int mi = 0; mi < MI; ++mi)
        for (int ni = 0; ni < NI; ++ni)
            for (int i = 0; i < 4; ++i) {
                int row = mbase + wr * (MI * 16) + mi * 16 + lg * 4 + i;
                int col = nbase + wc * (NI * 16) + ni * 16 + lr;
                float v = acc[mi][ni][i];
                if (EPI == 0) {
                    int sect = col >> 10, ch = col & 1023, hh = ch >> 6, dd = ch & 63;
                    int bI = row >> 10, wI = row & 1023;
                    size_t dst = ((size_t)(bI * NH + hh) * WW + wI) * DH + dd;
                    if (sect == 0) qb[dst] = f2bf(v * 0.125f);
                    else if (sect == 1) kb[dst] = f2bf(v);
                    else vb[dst] = f2bf(v);
                } else {
                    outp[(size_t)row * Ndim + col] = v;
                }
            }
}

// ---------- kernel 4: causal flash attention, dual q-tile balanced ----------
__global__ __launch_bounds__(512) void attn_kernel(const unsigned short* __restrict__ q,
                                                   const unsigned short* __restrict__ k,
                                                   const unsigned short* __restrict__ v,
                                                   unsigned short* __restrict__ aout) {
    __shared__ unsigned short Ks[64 * 64];
    __shared__ unsigned short Vt[64 * 64];      // transposed: Vt[d][kv]
    __shared__ unsigned short Ps0[128 * 64];
    __shared__ unsigned short Ps1[128 * 64];
    int t = threadIdx.x;
    int wid = t >> 6, lane = t & 63;
    int lr = lane & 15, lg = lane >> 4;
    int bh = blockIdx.y, bI = bh >> 4, hI = bh & 15;
    int p = blockIdx.x;                          // 0..3
    int qa = p * 128, qbv = (7 - p) * 128;
    int nktA = 2 * p + 2, nktB = 16 - 2 * p;

    bf16x8 qfA[2], qfB[2];
    {
        const unsigned short* qg = q + (size_t)bh * WW * DH;
        int r = wid * 16 + lr;
        for (int ks = 0; ks < 2; ++ks) {
            qfA[ks] = *(const bf16x8*)&qg[(size_t)(qa + r) * DH + ks * 32 + lg * 8];
            qfB[ks] = *(const bf16x8*)&qg[(size_t)(qbv + r) * DH + ks * 32 + lg * 8];
        }
    }

    float rmA[4], rlA[4], rmB[4], rlB[4];
    f32x4 oA[4] = {}, oB[4] = {};
    for (int i = 0; i < 4; ++i) { rmA[i] = rmB[i] = -1e30f; rlA[i] = rlB[i] = 0.f; }

    const unsigned short* kbase = k + (size_t)bh * WW * DH;
    const unsigned short* vbase = v + (size_t)bh * WW * DH;
    int dp = (t & 31) * 2, kb8 = (t >> 5) & 7;
    int tt = t & 255;
    int krow = tt >> 3, kc8 = (tt & 7) * 8;

    unsigned int vr[8]; int4 kr0, kr1;
    auto prefetch = [&](int tn) {
        if (wid < 4) {
            const unsigned short* vg = vbase + (size_t)tn * 64 * DH;
#pragma unroll
            for (int j = 0; j < 8; ++j)
                vr[j] = *(const unsigned int*)&vg[(size_t)(kb8 * 8 + j) * DH + dp];
        } else {
            const unsigned short* kg = kbase + (size_t)tn * 64 * DH;
            kr0 = *(const int4*)&kg[(size_t)krow * DH + kc8];
            kr1 = *(const int4*)&kg[(size_t)(krow + 32) * DH + kc8];
        }
    };
    prefetch(0);

    auto process = [&](const bf16x8* qf, int qbase, float* rm, float* rl, f32x4* o,
                       unsigned short* PsX, int tki) {
        f32x4 s[4] = {};
        for (int ks = 0; ks < 2; ++ks) {
            bf16x8 bfr[4];
            int cc = ks * 32 + lg * 8;
            for (int ni = 0; ni < 4; ++ni) {
                int r = ni * 16 + lr;
                bfr[ni] = *(const bf16x8*)&Ks[r * 64 + (cc ^ ((r & 7) << 3))];
            }
            __builtin_amdgcn_s_setprio(1);
            for (int ni = 0; ni < 4; ++ni)
                s[ni] = __builtin_amdgcn_mfma_f32_16x16x32_bf16(qf[ks], bfr[ni], s[ni], 0, 0, 0);
            __builtin_amdgcn_s_setprio(0);
        }
        int rowbase = qbase + wid * 16 + lg * 4;
        if (tki * 64 + 63 > qbase + wid * 16) {
            for (int ni = 0; ni < 4; ++ni)
                for (int i = 0; i < 4; ++i) {
                    int ki = tki * 64 + ni * 16 + lr;
                    if (ki > rowbase + i) s[ni][i] = -1e30f;
                }
        }
        for (int i = 0; i < 4; ++i) {
            float mx = fmaxf(fmaxf(s[0][i], s[1][i]), fmaxf(s[2][i], s[3][i]));
            for (int d = 8; d >= 1; d >>= 1) mx = fmaxf(mx, __shfl_xor(mx, d));
            float mnew = fmaxf(rm[i], mx);
            float sf = __expf(rm[i] - mnew);
            float psum = 0.f;
            for (int ni = 0; ni < 4; ++ni) {
                float pe = __expf(s[ni][i] - mnew);
                s[ni][i] = pe;
                psum += pe;
            }
            for (int d = 8; d >= 1; d >>= 1) psum += __shfl_xor(psum, d);
            rl[i] = rl[i] * sf + psum;
            rm[i] = mnew;
            for (int di = 0; di < 4; ++di) o[di][i] *= sf;
        }
        for (int ni = 0; ni < 4; ++ni)
            for (int i = 0; i < 4; ++i) {
                int r = wid * 16 + lg * 4 + i;
                PsX[r * 64 + ((ni * 16 + lr) ^ ((r & 7) << 3))] = f2bf(s[ni][i]);
            }
    };

    auto pvacc = [&](f32x4* o, const unsigned short* PsX) {
        for (int ks = 0; ks < 2; ++ks) {
            int cc = ks * 32 + lg * 8;
            int r = wid * 16 + lr;
            bf16x8 pa = *(const bf16x8*)&PsX[r * 64 + (cc ^ ((r & 7) << 3))];
            bf16x8 vbf[4];
            for (int di = 0; di < 4; ++di) {
                int rv = di * 16 + lr;
                vbf[di] = *(const bf16x8*)&Vt[rv * 64 + (cc ^ ((rv & 7) << 3))];
            }
            __builtin_amdgcn_s_setprio(1);
            for (int di = 0; di < 4; ++di)
                o[di] = __builtin_amdgcn_mfma_f32_16x16x32_bf16(pa, vbf[di], o[di], 0, 0, 0);
            __builtin_amdgcn_s_setprio(0);
        }
    };

    for (int tki = 0; tki < nktB; ++tki) {
        __syncthreads();
        if (wid < 4) {
            unsigned short lo[8], hi[8];
#pragma unroll
            for (int j = 0; j < 8; ++j) { lo[j] = (unsigned short)(vr[j] & 0xffffu);
                                          hi[j] = (unsigned short)(vr[j] >> 16); }
            *(int4*)&Vt[dp * 64 + ((kb8 * 8) ^ ((dp & 7) << 3))] = *(int4*)lo;
            int d1 = dp + 1;
            *(int4*)&Vt[d1 * 64 + ((kb8 * 8) ^ ((d1 & 7) << 3))] = *(int4*)hi;
        } else {
            *(int4*)&Ks[krow * 64 + (kc8 ^ ((krow & 7) << 3))] = kr0;
            int r1 = krow + 32;
            *(int4*)&Ks[r1 * 64 + (kc8 ^ ((r1 & 7) << 3))] = kr1;
        }
        if (tki + 1 < nktB) prefetch(tki + 1);
        __syncthreads();

        bool wB = (tki * 64 <= qbv + wid * 16 + 15);
        bool wA = (tki < nktA) && (tki * 64 <= qa + wid * 16 + 15);
        if (wB) process(qfB, qbv, rmB, rlB, oB, Ps1, tki);
        if (wA) process(qfA, qa, rmA, rlA, oA, Ps0, tki);
        __syncthreads();
        if (wB) pvacc(oB, Ps1);
        if (wA) pvacc(oA, Ps0);
    }

    for (int di = 0; di < 4; ++di)
        for (int i = 0; i < 4; ++i) {
            int dd = di * 16 + lr;
            int qrA = qa + wid * 16 + lg * 4 + i;
            int qrB = qbv + wid * 16 + lg * 4 + i;
            aout[((size_t)bI * WW + qrA) * CDIM + hI * DH + dd] = f2bf(oA[di][i] / rlA[i]);
            aout[((size_t)bI * WW + qrB) * CDIM + hI * DH + dd] = f2bf(oB[di][i] / rlB[i]);
        }
}

// ---------- launch ----------
extern "C" void kernel_launch(void* const* d_in, const int* in_sizes, int n_in,
                              void* d_out, int out_size, void* d_ws, size_t ws_size,
                              hipStream_t stream) {
    const float* x    = (const float*)d_in[0];
    const float* pos  = (const float*)d_in[1];
    const float* aw   = (const float*)d_in[2];
    const float* pw   = (const float*)d_in[3];
    const int*   mask = (const int*)d_in[4];
    float* out = (float*)d_out;
    float* word_f32 = out;                        // [4096,1024] f32
    float* proj_out = out + (size_t)MROWS * CDIM; // [4096,1024] f32

    const size_t MB = 1u << 20;
    char* ws = (char*)d_ws;
    unsigned short* word_bf = (unsigned short*)(ws);             // 8 MB
    unsigned short* awb     = (unsigned short*)(ws + 8 * MB);    // 6 MB
    unsigned short* pwb     = (unsigned short*)(ws + 14 * MB);   // 2 MB
    unsigned short* qb      = (unsigned short*)(ws + 16 * MB);   // 8 MB
    unsigned short* kb      = (unsigned short*)(ws + 24 * MB);   // 8 MB
    unsigned short* vb      = (unsigned short*)(ws + 32 * MB);   // 8 MB
    unsigned short* aob     = (unsigned short*)(ws + 40 * MB);   // 8 MB

    prep_kernel<<<8192, 256, 0, stream>>>(aw, pw, x, pos, mask, awb, pwb, word_f32, word_bf);

#ifdef HAVE_GLL
    // deep-pipelined QKV needs 112 KiB dynamic LDS; probe feasibility (deterministic, host-side)
    const int QKV_LDS = (2 * BUFS) * 2 + 64;   // 114752 B
    bool deep = false;
    {
        (void)hipFuncSetAttribute((const void*)gemm_qkv8_kernel,
                                  hipFuncAttributeMaxDynamicSharedMemorySize, QKV_LDS);
        int nb = 0;
        hipError_t e = hipOccupancyMaxActiveBlocksPerMultiprocessor(
            &nb, (const void*)gemm_qkv8_kernel, 512, (size_t)QKV_LDS);
        deep = (e == hipSuccess && nb >= 1);
        (void)hipGetLastError();   // clear any sticky error from the probe
    }
    if (deep) {
        // M=4096, N=3072: BM=256 BN=192 -> 16x16 = 256 blocks (1/CU)
        gemm_qkv8_kernel<<<dim3(3 * CDIM / 192, MROWS / 256), 512, QKV_LDS, stream>>>(
            word_bf, awb, qb, kb, vb);
    } else {
        gemm_nt_kernel<0, 128, 128, 2, 2, 4, 4><<<dim3(3 * CDIM / 128, MROWS / 128), 256, 0, stream>>>(
            word_bf, awb, MROWS, 3 * CDIM, CDIM, qb, kb, vb, nullptr);
    }
#else
    gemm_nt_kernel<0, 128, 128, 2, 2, 4, 4><<<dim3(3 * CDIM / 128, MROWS / 128), 256, 0, stream>>>(
        word_bf, awb, MROWS, 3 * CDIM, CDIM, qb, kb, vb, nullptr);
#endif

    attn_kernel<<<dim3(4, BB * NH), 512, 0, stream>>>(qb, kb, vb, aob);
    // proj: M=4096, N=1024, K=1024; 128x64 tiles, 512 blocks (2/CU)
    gemm_nt_kernel<1, 128, 64, 4, 1, 2, 4><<<dim3(CDIM / 64, MROWS / 128), 256, 0, stream>>>(
        aob, pwb, MROWS, CDIM, CDIM, nullptr, nullptr, nullptr, proj_out);
}